// Round 1
// baseline (1556.290 us; speedup 1.0000x reference)
//
#include <hip/hip_runtime.h>
#include <math.h>

#define NPG 128      // nodes per graph
#define HID 64
#define ICH 151
#define EPG 2048     // edges per graph
#define TPB 512      // 8 waves

__global__ __launch_bounds__(TPB) void gcn_fused(
    const float* __restrict__ x,       // [N,151]
    const int*   __restrict__ erow,    // [E]
    const int*   __restrict__ ecol,    // [E]
    const float* __restrict__ ew,      // [E]
    const float* __restrict__ W1,      // [151,64] row-major
    const float* __restrict__ b1,      // [64]
    const float* __restrict__ Wlin,    // [8192]
    const float* __restrict__ blin,    // [1]
    float* __restrict__ out)           // [B]
{
    // xs doubles as the aggregation accumulator (first 32 KB) after GEMM.
    __shared__ float xs[NPG * 152];    // 77824 B  (stride 152 -> 16B-aligned b128 rows)
    __shared__ float ws[152 * HID];    // 38912 B  (row 151 zeroed)
    __shared__ float hs[NPG * HID];    // 32768 B
    __shared__ float deg[NPG];
    __shared__ float dinv[NPG];
    __shared__ float red[TPB / 64];

    const int t    = threadIdx.x;
    const int g    = blockIdx.x;
    const int lane = t & 63;
    const int wv_id = t >> 6;

    // ---- Phase A: init deg (self-loop weight 1), stage W1 and x tile ----
    if (t < NPG) deg[t] = 1.0f;
    for (int idx = t; idx < 152 * HID; idx += TPB)
        ws[idx] = (idx < ICH * HID) ? W1[idx] : 0.0f;
    const float* xg = x + (size_t)g * (NPG * ICH);
    for (int idx = t; idx < NPG * ICH; idx += TPB) {
        unsigned r = (unsigned)idx / (unsigned)ICH;      // magic-mul div
        unsigned k = (unsigned)idx - r * (unsigned)ICH;
        xs[r * 152 + k] = xg[idx];
    }
    if (t < NPG) xs[t * 152 + 151] = 0.0f;               // zero k-pad
    __syncthreads();

    // ---- Phase B: edge-degree atomics (kept in regs for reuse) + GEMM ----
    int   er_[EPG / TPB];
    int   ec_[EPG / TPB];
    float ew_[EPG / TPB];
    const int ebase = g * EPG;
    #pragma unroll
    for (int it = 0; it < EPG / TPB; ++it) {
        int e = ebase + t + it * TPB;
        int rl = erow[e] & (NPG - 1);                    // local src
        int cl = ecol[e] & (NPG - 1);                    // local dst
        float we = ew[e];
        er_[it] = rl; ec_[it] = cl; ew_[it] = we;
        atomicAdd(&deg[cl], we);                          // ds_add_f32
    }

    // h = x @ W1 : wave owns 16 rows, lane owns column j
    float acc[16];
    #pragma unroll
    for (int i = 0; i < 16; ++i) acc[i] = 0.0f;
    {
        const int r0 = wv_id * 16;
        for (int k4 = 0; k4 < 38; ++k4) {
            // W1[k][lane] for 4 consecutive k (2-way bank alias = free)
            float w0 = ws[(4 * k4 + 0) * 64 + lane];
            float w1 = ws[(4 * k4 + 1) * 64 + lane];
            float w2 = ws[(4 * k4 + 2) * 64 + lane];
            float w3 = ws[(4 * k4 + 3) * 64 + lane];
            #pragma unroll
            for (int rr = 0; rr < 16; ++rr) {
                // wave-uniform broadcast b128 read
                const float4 xv = *(const float4*)&xs[(r0 + rr) * 152 + 4 * k4];
                acc[rr] += xv.x * w0 + xv.y * w1 + xv.z * w2 + xv.w * w3;
            }
        }
        #pragma unroll
        for (int rr = 0; rr < 16; ++rr)
            hs[(r0 + rr) * 64 + lane] = acc[rr];
    }
    __syncthreads();

    // ---- Phase C: dinv ----
    if (t < NPG) dinv[t] = rsqrtf(deg[t]);               // deg >= 1 always
    __syncthreads();

    // ---- Phase D: accumulator init with self-loop term (aliases xs) ----
    float* accs = xs;
    for (int idx = t; idx < NPG * HID; idx += TPB) {
        int i = idx >> 6;
        float di = dinv[i];
        accs[idx] = hs[idx] * di * di;                    // norm = dinv[i]*1*dinv[i]
    }
    __syncthreads();

    // ---- Phase E: edge scatter (lane-staggered channels -> 2-way banks) ----
    #pragma unroll
    for (int it = 0; it < EPG / TPB; ++it) {
        int rl = er_[it], cl = ec_[it];
        float nrm = dinv[rl] * ew_[it] * dinv[cl];
        #pragma unroll 8
        for (int jj = 0; jj < 64; ++jj) {
            int j = (lane + jj) & 63;
            atomicAdd(&accs[cl * 64 + j], nrm * hs[rl * 64 + j]);
        }
    }
    __syncthreads();

    // ---- Phase F: bias + relu + dot(Wlin) + sigmoid ----
    float partial = 0.0f;
    for (int idx = t; idx < NPG * HID; idx += TPB) {
        int j = idx & 63;
        float v = accs[idx] + b1[j];
        v = fmaxf(v, 0.0f);
        partial += v * Wlin[idx];
    }
    #pragma unroll
    for (int off = 32; off > 0; off >>= 1)
        partial += __shfl_down(partial, off, 64);
    if (lane == 0) red[wv_id] = partial;
    __syncthreads();
    if (t == 0) {
        float tot = blin[0];
        #pragma unroll
        for (int i = 0; i < TPB / 64; ++i) tot += red[i];
        out[g] = 1.0f / (1.0f + expf(-tot));
    }
}

extern "C" void kernel_launch(void* const* d_in, const int* in_sizes, int n_in,
                              void* d_out, int out_size, void* d_ws, size_t ws_size,
                              hipStream_t stream) {
    const float* x    = (const float*)d_in[0];
    const int*   ei   = (const int*)d_in[1];
    const float* ew   = (const float*)d_in[2];
    const float* W1   = (const float*)d_in[4];
    const float* b1   = (const float*)d_in[5];
    const float* Wlin = (const float*)d_in[6];
    const float* blin = (const float*)d_in[7];
    float* out = (float*)d_out;

    const int E = in_sizes[1] / 2;     // edge_index is [2, E]
    const int B = out_size;            // 2048 graphs

    gcn_fused<<<B, TPB, 0, stream>>>(x, ei, ei + E, ew, W1, b1, Wlin, blin, out);
}

// Round 2
// 365.556 us; speedup vs baseline: 4.2573x; 4.2573x over previous
//
#include <hip/hip_runtime.h>
#include <math.h>

#define NPG 128      // nodes per graph
#define HID 64
#define ICH 151
#define EPG 2048     // edges per graph
#define TPB 512      // 8 waves
#define EPT (EPG / TPB)   // 4 edges per thread

__global__ __launch_bounds__(TPB) void gcn_fused(
    const float* __restrict__ x,       // [N,151]
    const int*   __restrict__ erow,    // [E]
    const int*   __restrict__ ecol,    // [E]
    const float* __restrict__ ew,      // [E]
    const float* __restrict__ W1,      // [151,64] row-major
    const float* __restrict__ b1,      // [64]
    const float* __restrict__ Wlin,    // [8192]
    const float* __restrict__ blin,    // [1]
    float* __restrict__ out)           // [B]
{
    // xs is used by the GEMM, then its first 16KB is reused for sorted edges.
    __shared__ float xs[NPG * 152];    // 77824 B (stride 152 -> 16B-aligned b128)
    __shared__ float ws[152 * HID];    // 38912 B (row 151 zeroed)
    __shared__ float hs[NPG * HID];    // 32768 B
    __shared__ float deg[NPG];
    __shared__ float dinv[NPG];
    __shared__ int   cnt[NPG];
    __shared__ int   off[NPG + 1];
    __shared__ int   cur[NPG];
    __shared__ float red[TPB / 64];

    const int t     = threadIdx.x;
    const int g     = blockIdx.x;
    const int lane  = t & 63;
    const int wv_id = t >> 6;

    // ---- Phase A: init deg/cnt, stage W1 and x tile ----
    if (t < NPG) { deg[t] = 1.0f; cnt[t] = 0; }
    for (int idx = t; idx < 152 * HID; idx += TPB)
        ws[idx] = (idx < ICH * HID) ? W1[idx] : 0.0f;
    const float* xg = x + (size_t)g * (NPG * ICH);
    for (int idx = t; idx < NPG * ICH; idx += TPB) {
        unsigned r = (unsigned)idx / (unsigned)ICH;
        unsigned k = (unsigned)idx - r * (unsigned)ICH;
        xs[r * 152 + k] = xg[idx];
    }
    if (t < NPG) xs[t * 152 + 151] = 0.0f;               // zero k-pad
    __syncthreads();                                      // sync1

    // ---- Phase B: edge load (kept in regs) + deg/hist atomics + GEMM ----
    int   er_[EPT];
    int   ec_[EPT];
    float ew_[EPT];
    const int ebase = g * EPG;
    #pragma unroll
    for (int it = 0; it < EPT; ++it) {
        int e = ebase + t + it * TPB;
        int rl = erow[e] & (NPG - 1);                    // local src
        int cl = ecol[e] & (NPG - 1);                    // local dst
        float we = ew[e];
        er_[it] = rl; ec_[it] = cl; ew_[it] = we;
        atomicAdd(&deg[cl], we);
        atomicAdd(&cnt[cl], 1);
    }

    // h = x @ W1 : wave owns 16 rows, lane owns column `lane`
    float acc[16];
    #pragma unroll
    for (int i = 0; i < 16; ++i) acc[i] = 0.0f;
    {
        const int r0 = wv_id * 16;
        for (int k4 = 0; k4 < 38; ++k4) {
            float w0 = ws[(4 * k4 + 0) * 64 + lane];
            float w1 = ws[(4 * k4 + 1) * 64 + lane];
            float w2 = ws[(4 * k4 + 2) * 64 + lane];
            float w3 = ws[(4 * k4 + 3) * 64 + lane];
            #pragma unroll
            for (int rr = 0; rr < 16; ++rr) {
                const float4 xv = *(const float4*)&xs[(r0 + rr) * 152 + 4 * k4];
                acc[rr] += xv.x * w0 + xv.y * w1 + xv.z * w2 + xv.w * w3;
            }
        }
        #pragma unroll
        for (int rr = 0; rr < 16; ++rr)
            hs[(r0 + rr) * 64 + lane] = acc[rr];
    }
    __syncthreads();                                      // sync2 (GEMM + hist done)

    // ---- Phase C: dinv (waves 2-3) + exclusive scan of cnt (wave 0) ----
    if (t >= 128 && t < 256) {
        int i = t - 128;
        dinv[i] = rsqrtf(deg[i]);                         // deg >= 1 always
    }
    if (wv_id == 0) {
        int a = cnt[2 * lane], b = cnt[2 * lane + 1];
        int s = a + b;
        int incl = s;
        #pragma unroll
        for (int d = 1; d < 64; d <<= 1) {
            int n = __shfl_up(incl, d, 64);
            if (lane >= d) incl += n;
        }
        int exc = incl - s;
        off[2 * lane] = exc;      off[2 * lane + 1] = exc + a;
        cur[2 * lane] = exc;      cur[2 * lane + 1] = exc + a;
        if (lane == 63) off[NPG] = incl;                  // = EPG
    }
    __syncthreads();                                      // sync3

    // ---- Phase D: counting-sort scatter into xs-aliased buffers ----
    int*   es_rl  = (int*)xs;                             // [EPG]  8KB
    float* es_nrm = (float*)(xs + EPG);                   // [EPG]  8KB
    #pragma unroll
    for (int it = 0; it < EPT; ++it) {
        int rl = er_[it], cl = ec_[it];
        int pos = atomicAdd(&cur[cl], 1);
        es_rl[pos]  = rl;
        es_nrm[pos] = dinv[rl] * ew_[it] * dinv[cl];
    }
    __syncthreads();                                      // sync4

    // ---- Phase E: gather aggregation + bias + relu + Wlin dot ----
    const float b1v = b1[lane];
    float partial = 0.0f;
    {
        const int i0 = wv_id * 16;
        for (int ii = 0; ii < 16; ++ii) {
            int i = i0 + ii;                              // wave-uniform node
            float di = dinv[i];
            float a2 = di * di * hs[i * 64 + lane];       // self-loop term
            int s = off[i], e = off[i + 1];
            for (int eidx = s; eidx < e; ++eidx) {        // uniform bounds
                int   rl = es_rl[eidx];                   // broadcast read
                float nr = es_nrm[eidx];                  // broadcast read
                a2 += nr * hs[rl * 64 + lane];            // conflict-free row
            }
            float v = fmaxf(a2 + b1v, 0.0f);
            partial += v * Wlin[i * 64 + lane];
        }
    }
    #pragma unroll
    for (int o = 32; o > 0; o >>= 1)
        partial += __shfl_down(partial, o, 64);
    if (lane == 0) red[wv_id] = partial;
    __syncthreads();                                      // sync5
    if (t == 0) {
        float tot = blin[0];
        #pragma unroll
        for (int i = 0; i < TPB / 64; ++i) tot += red[i];
        out[g] = 1.0f / (1.0f + expf(-tot));
    }
}

extern "C" void kernel_launch(void* const* d_in, const int* in_sizes, int n_in,
                              void* d_out, int out_size, void* d_ws, size_t ws_size,
                              hipStream_t stream) {
    const float* x    = (const float*)d_in[0];
    const int*   ei   = (const int*)d_in[1];
    const float* ew   = (const float*)d_in[2];
    const float* W1   = (const float*)d_in[4];
    const float* b1   = (const float*)d_in[5];
    const float* Wlin = (const float*)d_in[6];
    const float* blin = (const float*)d_in[7];
    float* out = (float*)d_out;

    const int E = in_sizes[1] / 2;     // edge_index is [2, E]
    const int B = out_size;            // 2048 graphs

    gcn_fused<<<B, TPB, 0, stream>>>(x, ei, ei + E, ew, W1, b1, Wlin, blin, out);
}

// Round 3
// 155.075 us; speedup vs baseline: 10.0357x; 2.3573x over previous
//
#include <hip/hip_runtime.h>
#include <math.h>

#define NPG 128      // nodes per graph
#define HID 64
#define ICH 151
#define EPG 2048     // edges per graph
#define TPB 512      // 8 waves
#define EPT (EPG / TPB)
#define KP  160      // padded K: 5 MFMA k-steps of 32
#define BTS 168      // W1^T row stride in bf16 elems (336 B, 16B-aligned)

typedef __attribute__((ext_vector_type(8))) short  short8;   // bf16x8 frag
typedef __attribute__((ext_vector_type(4))) float  floatx4;  // f32x4 acc

__device__ __forceinline__ unsigned short f2bf_rne(float v) {
    unsigned u = __builtin_bit_cast(unsigned, v);
    return (unsigned short)((u + 0x7fffu + ((u >> 16) & 1u)) >> 16);
}
__device__ __forceinline__ float bf2f(unsigned short b) {
    return __builtin_bit_cast(float, (unsigned)b << 16);
}

__global__ __launch_bounds__(TPB, 4) void gcn_fused(
    const float* __restrict__ x,       // [N,151]
    const int*   __restrict__ erow,    // [E]
    const int*   __restrict__ ecol,    // [E]
    const float* __restrict__ ew,      // [E]
    const float* __restrict__ W1,      // [151,64] row-major
    const float* __restrict__ b1,      // [64]
    const float* __restrict__ Wlin,    // [8192]
    const float* __restrict__ blin,    // [1]
    float* __restrict__ out)           // [B]
{
    // Bt planes (hi, lo) of W1^T; aliased by sorted-edge buffer after GEMM.
    __shared__ __align__(16) char smem[2 * HID * BTS * 2];   // 43008 B
    __shared__ float hs[NPG * HID];                          // 32768 B
    __shared__ float deg[NPG];
    __shared__ float dinv[NPG];
    __shared__ int   cnt[NPG];
    __shared__ int   off_[NPG + 1];
    __shared__ int   cur[NPG];
    __shared__ float red[TPB / 64];

    short* bt = (short*)smem;          // [plane][col][BTS]
    int2*  es = (int2*)smem;           // [EPG] {rl, nrm-bits} after GEMM

    const int t    = threadIdx.x;
    const int g    = blockIdx.x;
    const int lane = t & 63;
    const int wv   = t >> 6;

    // ---- Phase A: init deg/cnt; stage W1^T as bf16 hi/lo planes ----
    if (t < NPG) { deg[t] = 1.0f; cnt[t] = 0; }
    {
        const int c  = t & 63;
        const int k0 = (t >> 6) * 2;                  // even k start
        for (int k = k0; k < BTS; k += 16) {
            float w0 = (k     < ICH) ? W1[k * HID + c]       : 0.0f;
            float w1 = (k + 1 < ICH) ? W1[(k + 1) * HID + c] : 0.0f;
            unsigned short h0 = f2bf_rne(w0), h1 = f2bf_rne(w1);
            unsigned short l0 = f2bf_rne(w0 - bf2f(h0));
            unsigned short l1 = f2bf_rne(w1 - bf2f(h1));
            *(unsigned*)&bt[c * BTS + k] = (unsigned)h0 | ((unsigned)h1 << 16);
            *(unsigned*)&bt[HID * BTS + c * BTS + k] = (unsigned)l0 | ((unsigned)l1 << 16);
        }
    }

    // ---- A-fragments: x rows direct global -> regs -> bf16 hi/lo ----
    const int c16 = lane & 15;
    const int kq  = (lane >> 4) * 8;
    short8 ahi[5], alo[5];
    {
        const float* xr = x + (size_t)g * (NPG * ICH) + (wv * 16 + c16) * ICH;
        #pragma unroll
        for (int s = 0; s < 5; ++s) {
            #pragma unroll
            for (int j = 0; j < 8; ++j) {
                int k = s * 32 + kq + j;
                float v = (k < ICH) ? xr[k] : 0.0f;
                unsigned short hb = f2bf_rne(v);
                ahi[s][j] = (short)hb;
                alo[s][j] = (short)f2bf_rne(v - bf2f(hb));
            }
        }
    }
    __syncthreads();                                  // sync1: Bt + deg/cnt ready

    // ---- Phase B: edge pass 1 (deg/hist atomics) + MFMA GEMM ----
    const int ebase = g * EPG;
    #pragma unroll
    for (int it = 0; it < EPT; ++it) {
        int e = ebase + t + it * TPB;
        int cl = ecol[e] & (NPG - 1);
        atomicAdd(&deg[cl], ew[e]);
        atomicAdd(&cnt[cl], 1);
    }

    #pragma unroll
    for (int n = 0; n < 4; ++n) {
        floatx4 acc = {0.0f, 0.0f, 0.0f, 0.0f};
        #pragma unroll
        for (int s = 0; s < 5; ++s) {
            const short* bp = bt + (n * 16 + c16) * BTS + s * 32 + kq;
            short8 bh = *(const short8*)bp;
            short8 bl = *(const short8*)(bp + HID * BTS);
            acc = __builtin_amdgcn_mfma_f32_16x16x32_bf16(ahi[s], bh, acc, 0, 0, 0);
            acc = __builtin_amdgcn_mfma_f32_16x16x32_bf16(alo[s], bh, acc, 0, 0, 0);
            acc = __builtin_amdgcn_mfma_f32_16x16x32_bf16(ahi[s], bl, acc, 0, 0, 0);
        }
        #pragma unroll
        for (int r = 0; r < 4; ++r)
            hs[(wv * 16 + (lane >> 4) * 4 + r) * HID + n * 16 + c16] = acc[r];
    }
    __syncthreads();                                  // sync2: hs + hist done, Bt dead

    // ---- Phase C: dinv + exclusive scan of cnt (wave 0) ----
    if (t >= 128 && t < 256) {
        int i = t - 128;
        dinv[i] = rsqrtf(deg[i]);                     // deg >= 1 always
    }
    if (wv == 0) {
        int a = cnt[2 * lane], b = cnt[2 * lane + 1];
        int s = a + b;
        int incl = s;
        #pragma unroll
        for (int d = 1; d < 64; d <<= 1) {
            int n = __shfl_up(incl, d, 64);
            if (lane >= d) incl += n;
        }
        int exc = incl - s;
        off_[2 * lane] = exc;     off_[2 * lane + 1] = exc + a;
        cur[2 * lane]  = exc;     cur[2 * lane + 1]  = exc + a;
        if (lane == 63) off_[NPG] = incl;             // = EPG
    }
    __syncthreads();                                  // sync3

    // ---- Phase D: counting-sort scatter (re-read edges; es aliases Bt) ----
    #pragma unroll
    for (int it = 0; it < EPT; ++it) {
        int e  = ebase + t + it * TPB;
        int rl = erow[e] & (NPG - 1);
        int cl = ecol[e] & (NPG - 1);
        float nrm = dinv[rl] * ew[e] * dinv[cl];
        int pos = atomicAdd(&cur[cl], 1);
        es[pos] = make_int2(rl, __builtin_bit_cast(int, nrm));
    }
    __syncthreads();                                  // sync4

    // ---- Phase E: gather + bias + relu + Wlin dot ----
    const float b1v = b1[lane];
    float partial = 0.0f;
    {
        const int i0 = wv * 16;
        for (int ii = 0; ii < 16; ++ii) {
            int i = i0 + ii;                          // wave-uniform node
            float di = dinv[i];
            float a2 = di * di * hs[i * HID + lane];  // self-loop term
            int sb = off_[i], eb = off_[i + 1];
            for (int eidx = sb; eidx < eb; ++eidx) {
                int2 m = es[eidx];                    // broadcast b64
                a2 += __builtin_bit_cast(float, m.y) * hs[m.x * HID + lane];
            }
            float v = fmaxf(a2 + b1v, 0.0f);
            partial += v * Wlin[i * HID + lane];
        }
    }
    #pragma unroll
    for (int o = 32; o > 0; o >>= 1)
        partial += __shfl_down(partial, o, 64);
    if (lane == 0) red[wv] = partial;
    __syncthreads();                                  // sync5
    if (t == 0) {
        float tot = blin[0];
        #pragma unroll
        for (int i = 0; i < TPB / 64; ++i) tot += red[i];
        out[g] = 1.0f / (1.0f + expf(-tot));
    }
}

extern "C" void kernel_launch(void* const* d_in, const int* in_sizes, int n_in,
                              void* d_out, int out_size, void* d_ws, size_t ws_size,
                              hipStream_t stream) {
    const float* x    = (const float*)d_in[0];
    const int*   ei   = (const int*)d_in[1];
    const float* ew   = (const float*)d_in[2];
    const float* W1   = (const float*)d_in[4];
    const float* b1   = (const float*)d_in[5];
    const float* Wlin = (const float*)d_in[6];
    const float* blin = (const float*)d_in[7];
    float* out = (float*)d_out;

    const int E = in_sizes[1] / 2;     // edge_index is [2, E]
    const int B = out_size;            // 2048 graphs

    gcn_fused<<<B, TPB, 0, stream>>>(x, ei, ei + E, ew, W1, b1, Wlin, blin, out);
}

// Round 4
// 85.444 us; speedup vs baseline: 18.2142x; 1.8149x over previous
//
#include <hip/hip_runtime.h>
#include <math.h>

#define NPG 128      // nodes per graph
#define HID 64
#define ICH 151
#define EPG 2048     // edges per graph
#define TPB 512      // 8 waves
#define EPT (EPG / TPB)   // 4 edges per thread per pass
#define BTS 168      // W1^T row stride in bf16 elems (336 B, 16B-aligned)
#define AS  136      // A row stride in floats (544 B, 16B-aligned)
#define HTS 136      // h^T row stride in bf16 elems (272 B, 16B-aligned)

typedef __attribute__((ext_vector_type(8))) short  short8;   // bf16x8 frag
typedef __attribute__((ext_vector_type(4))) float  floatx4;  // f32x4 acc

static __device__ __forceinline__ unsigned short f2bf(float v) {
    unsigned u = __builtin_bit_cast(unsigned, v);
    return (unsigned short)((u + 0x7fffu + ((u >> 16) & 1u)) >> 16);
}

__global__ __launch_bounds__(TPB, 6) void gcn_fused(
    const float* __restrict__ x,       // [N,151]
    const int*   __restrict__ erow,    // [E]
    const int*   __restrict__ ecol,    // [E]
    const float* __restrict__ ew,      // [E]
    const float* __restrict__ W1,      // [151,64] row-major
    const float* __restrict__ b1,      // [64]
    const float* __restrict__ Wlin,    // [8192]
    const float* __restrict__ blin,    // [1]
    float* __restrict__ out)           // [B]
{
    // As (fp32 half-adjacency, 34816B) is aliased by bt (W1^T bf16, 21504B):
    // bt is dead after the GEMM, A is built after.
    __shared__ __align__(16) float As[64 * AS];        // 34816 B
    __shared__ __align__(16) short ht[HID * HTS];      // 17408 B  h^T bf16
    __shared__ float deg[NPG];
    __shared__ float dinv[NPG];
    __shared__ float red[TPB / 64];

    short* bt = (short*)As;                            // [64][BTS]

    const int t    = threadIdx.x;
    const int g    = blockIdx.x;
    const int lane = t & 63;
    const int wv   = t >> 6;
    const int c16  = lane & 15;
    const int kq   = (lane >> 4) * 8;

    // ---- Phase A: init deg; stage W1^T bf16; load x fragments to regs ----
    if (t < NPG) deg[t] = 1.0f;
    {
        const int c  = t & 63;
        const int k0 = (t >> 6) * 2;
        for (int k = k0; k < BTS; k += 16) {
            float w0 = (k     < ICH) ? W1[k * HID + c]       : 0.0f;
            float w1 = (k + 1 < ICH) ? W1[(k + 1) * HID + c] : 0.0f;
            *(unsigned*)&bt[c * BTS + k] =
                (unsigned)f2bf(w0) | ((unsigned)f2bf(w1) << 16);
        }
    }
    short8 af[5];                                      // x frags (bf16)
    {
        const float* xr = x + (size_t)g * (NPG * ICH) + (wv * 16 + c16) * ICH;
        #pragma unroll
        for (int s = 0; s < 5; ++s) {
            #pragma unroll
            for (int j = 0; j < 8; ++j) {
                int k = s * 32 + kq + j;
                af[s][j] = (short)f2bf((k < ICH) ? xr[k] : 0.0f);
            }
        }
    }
    __syncthreads();                                   // sync1

    // ---- Phase B: deg atomics + GEMM h = x @ W1, write h^T bf16 ----
    const int ebase = g * EPG;
    #pragma unroll
    for (int it = 0; it < EPT; ++it) {
        int e = ebase + t + it * TPB;
        atomicAdd(&deg[ecol[e] & (NPG - 1)], ew[e]);
    }
    #pragma unroll
    for (int n = 0; n < 4; ++n) {
        floatx4 acc = {0.0f, 0.0f, 0.0f, 0.0f};
        #pragma unroll
        for (int s = 0; s < 5; ++s) {
            short8 b = *(const short8*)&bt[(n * 16 + c16) * BTS + s * 32 + kq];
            acc = __builtin_amdgcn_mfma_f32_16x16x32_bf16(af[s], b, acc, 0, 0, 0);
        }
        // D layout: row = (lane>>4)*4 + r, col = n*16 + c16  -> ht[col][row]
        unsigned lo = (unsigned)f2bf(acc[0]) | ((unsigned)f2bf(acc[1]) << 16);
        unsigned hi = (unsigned)f2bf(acc[2]) | ((unsigned)f2bf(acc[3]) << 16);
        int col = n * 16 + c16;
        int row = wv * 16 + (lane >> 4) * 4;
        *(int2*)&ht[col * HTS + row] = make_int2((int)lo, (int)hi);
    }
    __syncthreads();                                   // sync2 (deg + ht done, bt dead)

    // ---- Phase C: dinv ----
    if (t < NPG) dinv[t] = rsqrtf(deg[t]);             // deg >= 1 always
    __syncthreads();                                   // sync3

    // ---- Phases D/E: two half-passes of dense-A build + MFMA aggregation ----
    float partial = 0.0f;
    const int mrow = (wv >> 1) * 16 + c16;             // A-frag row in half (0..63)
    for (int half = 0; half < 2; ++half) {
        // zero A (fp32, 64 x AS)
        for (int z = t; z < 64 * AS / 4; z += TPB)
            ((floatx4*)As)[z] = (floatx4){0.0f, 0.0f, 0.0f, 0.0f};
        __syncthreads();

        // scatter edges with dst in this half; diagonal = self-loop dinv^2
        #pragma unroll
        for (int it = 0; it < EPT; ++it) {
            int e  = ebase + t + it * TPB;
            int rl = erow[e] & (NPG - 1);
            int cl = ecol[e] & (NPG - 1);
            if ((cl >> 6) == half) {
                float nrm = dinv[rl] * ew[e] * dinv[cl];
                atomicAdd(&As[(cl & 63) * AS + rl], nrm);
            }
        }
        if (t < 64) {
            int i = half * 64 + t;
            atomicAdd(&As[t * AS + i], dinv[i] * dinv[i]);
        }
        __syncthreads();

        // aggregation MFMA: wave wv -> mtile = wv>>1, n-tiles {(wv&1)*2, +1}
        short8 afr[4];
        #pragma unroll
        for (int ks = 0; ks < 4; ++ks) {
            const float* ap = &As[mrow * AS + ks * 32 + kq];
            floatx4 a0 = *(const floatx4*)ap;
            floatx4 a1 = *(const floatx4*)(ap + 4);
            short8 v;
            v[0] = (short)f2bf(a0[0]); v[1] = (short)f2bf(a0[1]);
            v[2] = (short)f2bf(a0[2]); v[3] = (short)f2bf(a0[3]);
            v[4] = (short)f2bf(a1[0]); v[5] = (short)f2bf(a1[1]);
            v[6] = (short)f2bf(a1[2]); v[7] = (short)f2bf(a1[3]);
            afr[ks] = v;
        }
        #pragma unroll
        for (int nn = 0; nn < 2; ++nn) {
            int nt = (wv & 1) * 2 + nn;
            floatx4 acc = {0.0f, 0.0f, 0.0f, 0.0f};
            #pragma unroll
            for (int ks = 0; ks < 4; ++ks) {
                short8 b = *(const short8*)&ht[(nt * 16 + c16) * HTS + ks * 32 + kq];
                acc = __builtin_amdgcn_mfma_f32_16x16x32_bf16(afr[ks], b, acc, 0, 0, 0);
            }
            int col = nt * 16 + c16;
            float b1v = b1[col];
            int row0 = half * 64 + (wv >> 1) * 16 + (lane >> 4) * 4;
            #pragma unroll
            for (int r = 0; r < 4; ++r) {
                float v = fmaxf(acc[r] + b1v, 0.0f);
                partial += v * Wlin[(row0 + r) * HID + col];
            }
        }
        __syncthreads();                               // A reads done before re-zero
    }

    // ---- Phase F: block reduction + sigmoid ----
    #pragma unroll
    for (int o = 32; o > 0; o >>= 1)
        partial += __shfl_down(partial, o, 64);
    if (lane == 0) red[wv] = partial;
    __syncthreads();
    if (t == 0) {
        float tot = blin[0];
        #pragma unroll
        for (int i = 0; i < TPB / 64; ++i) tot += red[i];
        out[g] = 1.0f / (1.0f + expf(-tot));
    }
}

extern "C" void kernel_launch(void* const* d_in, const int* in_sizes, int n_in,
                              void* d_out, int out_size, void* d_ws, size_t ws_size,
                              hipStream_t stream) {
    const float* x    = (const float*)d_in[0];
    const int*   ei   = (const int*)d_in[1];
    const float* ew   = (const float*)d_in[2];
    const float* W1   = (const float*)d_in[4];
    const float* b1   = (const float*)d_in[5];
    const float* Wlin = (const float*)d_in[6];
    const float* blin = (const float*)d_in[7];
    float* out = (float*)d_out;

    const int E = in_sizes[1] / 2;     // edge_index is [2, E]
    const int B = out_size;            // 2048 graphs

    gcn_fused<<<B, TPB, 0, stream>>>(x, ei, ei + E, ew, W1, b1, Wlin, blin, out);
}